// Round 10
// baseline (297.293 us; speedup 1.0000x reference)
//
#include <hip/hip_runtime.h>
#include <hip/hip_bf16.h>
#include <cstdint>

typedef unsigned short u16;
typedef __attribute__((ext_vector_type(8))) _Float16 half8;  // 8 f16 in 4 VGPRs
typedef __attribute__((ext_vector_type(2))) __fp16 fp16x2;
typedef __attribute__((ext_vector_type(4))) float f32x4;
typedef __attribute__((ext_vector_type(4))) unsigned u32x4;

#define B_ 4
#define C_ 256
#define N_ 4096
#define M_ 4096
#define QB 32
#define KVB 32
#define NT 64                 // per-block KV iters (M-split x2)
#define LOG2E 1.44269504088896340736f

__device__ __forceinline__ u16 f2h(float x){
  _Float16 h = (_Float16)x;
  return __builtin_bit_cast(u16, h);
}
__device__ __forceinline__ float h2f(u16 h){
  return (float)__builtin_bit_cast(_Float16, h);
}
__device__ __forceinline__ unsigned pkrtz(float a, float b){
  fp16x2 h = __builtin_amdgcn_cvt_pkrtz(a, b);
  return __builtin_bit_cast(unsigned, h);
}
__device__ __forceinline__ float sum2(unsigned w){
  fp16x2 h = __builtin_bit_cast(fp16x2, w);
  return (float)h.x + (float)h.y;
}
__device__ __forceinline__ void gll16(const void* gsrc, void* ldst){
  __builtin_amdgcn_global_load_lds(
      (const __attribute__((address_space(1))) unsigned int*)gsrc,
      (__attribute__((address_space(3))) unsigned int*)ldst, 16, 0, 0);
}
// LDS-only barrier: does NOT drain vmcnt -> in-flight global_load_lds survives
__device__ __forceinline__ void bar_lds(){
  asm volatile("s_waitcnt lgkmcnt(0)" ::: "memory");
  __builtin_amdgcn_s_barrier();
}
// se^2 hi/lo with guaranteed packed-f16 lowering (residual exact in f16)
__device__ __forceinline__ void sq_hl(half8 v, half8& h2, half8& l2){
  u32x4 vw = __builtin_bit_cast(u32x4, v);
  u32x4 hw, lw;
  #pragma unroll
  for (int j=0;j<4;j++){
    unsigned h, l;
    asm("v_pk_mul_f16 %0, %1, %1" : "=v"(h) : "v"(vw[j]));
    asm("v_pk_fma_f16 %0, %1, %1, %2 neg_lo:[0,0,1] neg_hi:[0,0,1]"
        : "=v"(l) : "v"(vw[j]), "v"(h));
    hw[j] = h; lw[j] = l;
  }
  h2 = __builtin_bit_cast(half8, hw);
  l2 = __builtin_bit_cast(half8, lw);
}

// ---------------- K1: instance-norm stats (mean, rstd) per (b,c) ----------------
__global__ __launch_bounds__(256) void k_stats(const float* __restrict__ q,
                                               const float* __restrict__ k,
                                               float* __restrict__ sq,
                                               float* __restrict__ sk){
  int row = blockIdx.x;
  const float* src = (row < 1024) ? (q + (size_t)row * N_)
                                  : (k + (size_t)(row - 1024) * N_);
  float s = 0.f, ss = 0.f;
  for (int i = threadIdx.x; i < N_/4; i += 256){
    float4 v = ((const float4*)src)[i];
    s  += v.x + v.y + v.z + v.w;
    ss += v.x*v.x + v.y*v.y + v.z*v.z + v.w*v.w;
  }
  #pragma unroll
  for (int off = 32; off >= 1; off >>= 1){
    s  += __shfl_down(s, off);
    ss += __shfl_down(ss, off);
  }
  __shared__ float rs[4], rss[4];
  int w = threadIdx.x >> 6;
  if ((threadIdx.x & 63) == 0){ rs[w] = s; rss[w] = ss; }
  __syncthreads();
  if (threadIdx.x == 0){
    s  = rs[0]+rs[1]+rs[2]+rs[3];
    ss = rss[0]+rss[1]+rss[2]+rss[3];
    float m   = s * (1.f/N_);
    float var = ss * (1.f/N_) - m*m;
    float r   = rsqrtf(fmaxf(var, 0.f) + 1e-5f);
    float* dst = (row < 1024) ? (sq + row*2) : (sk + (row-1024)*2);
    dst[0] = m; dst[1] = r;
  }
}

// ---------------- K1b: fold inorm into weights; f16 hi/lo, frag-major layout ----
__global__ __launch_bounds__(64) void k_wprep(
    const float* __restrict__ wq, const float* __restrict__ bq,
    const float* __restrict__ wk, const float* __restrict__ bk,
    const float* __restrict__ wsw, const float* __restrict__ bs,
    const float* __restrict__ sq, const float* __restrict__ sk,
    u16* __restrict__ wh, u16* __restrict__ wl, float* __restrict__ bias2)
{
  int co = blockIdx.x, z = blockIdx.y;
  int lane = threadIdx.x;
  const float* W; const float* bias; const float* st = nullptr; float sc = 1.f;
  if (z < 4){ W = wq; bias = bq; st = sq + z*512; sc = LOG2E; }
  else if (z < 8){ W = wk; bias = bk; st = sk + (z-4)*512; }
  else { W = wsw; bias = bs; }
  float4 wv = *(const float4*)(W + co*256 + lane*4);
  float w4[4] = {wv.x, wv.y, wv.z, wv.w};
  float vs[4];
  float bsum = 0.f;
  if (st){
    float4 s0 = *(const float4*)(st + lane*8);
    float4 s1 = *(const float4*)(st + lane*8 + 4);
    float mm[4] = {s0.x, s0.z, s1.x, s1.z};
    float rr[4] = {s0.y, s0.w, s1.y, s1.w};
    #pragma unroll
    for (int i=0;i<4;i++){
      vs[i] = w4[i]*rr[i]*sc;
      bsum += w4[i]*rr[i]*mm[i];
    }
  } else {
    #pragma unroll
    for (int i=0;i<4;i++) vs[i] = w4[i];
  }
  u16 hi[4], lo[4];
  #pragma unroll
  for (int i=0;i<4;i++){
    hi[i] = f2h(vs[i]);
    lo[i] = f2h(vs[i] - h2f(hi[i]));
  }
  size_t idx = ((size_t)(z*8 + (lane>>3))*256 + co)*32 + ((lane>>1)&3)*8 + (lane&1)*4;
  *(uint2*)(wh + idx) = make_uint2((unsigned)hi[0] | ((unsigned)hi[1]<<16),
                                   (unsigned)hi[2] | ((unsigned)hi[3]<<16));
  *(uint2*)(wl + idx) = make_uint2((unsigned)lo[0] | ((unsigned)lo[1]<<16),
                                   (unsigned)lo[2] | ((unsigned)lo[3]<<16));
  #pragma unroll
  for (int off = 32; off >= 1; off >>= 1) bsum += __shfl_down(bsum, off);
  if (lane == 0) bias2[z*256 + co] = sc*(bias[co] - bsum);
}

// ---------------- K2: conv1x1 via MFMA (f16 hi/lo weights, raw f16 inputs) ------
__global__ __launch_bounds__(256, 3) void k_conv(
    const float* __restrict__ q, const float* __restrict__ kk,
    const u16* __restrict__ wh, const u16* __restrict__ wl,
    const float* __restrict__ bias2,
    u16* __restrict__ qe, u16* __restrict__ kt, u16* __restrict__ se)
{
  __shared__ u16 XT[64*256];   // 32KB
  const int tid = threadIdx.x;
  const int spt = blockIdx.x, bz = blockIdx.y;
  const int b = bz / 3, mode = bz - b*3;
  const int sp0 = spt*64;
  const float* X = (mode==0 ? q : kk) + (size_t)b*C_*N_;
  const int z = (mode==0) ? b : (mode==1 ? 4+b : 8);
  const u16* whp = wh + (size_t)z*8*256*32;
  const u16* wlp = wl + (size_t)z*8*256*32;
  const float* bp = bias2 + z*256;

  {
    int kc_l = tid & 15, spq = tid >> 4;
    #pragma unroll
    for (int i=0;i<16;i++){
      int kc = i*16 + kc_l;
      float4 v = *(const float4*)(X + (size_t)kc*N_ + sp0 + spq*4);
      float vv[4] = {v.x, v.y, v.z, v.w};
      #pragma unroll
      for (int e=0;e<4;e++){
        int sp = spq*4 + e;
        int byte = sp*512 + (((kc>>3) ^ (sp&7)) << 4) + (kc&7)*2;
        *(u16*)((char*)XT + byte) = f2h(vv[e]);
      }
    }
  }
  __syncthreads();

  const int wid = tid>>6, lane = tid&63, l15 = lane&15, lg = lane>>4;
  f32x4 acc[4][4];
  #pragma unroll
  for (int i=0;i<4;i++)
    #pragma unroll
    for (int j=0;j<4;j++) acc[i][j] = (f32x4)(0.f);

  #pragma unroll
  for (int ks=0; ks<8; ++ks){
    half8 xf[4];
    #pragma unroll
    for (int st=0; st<4; ++st)
      xf[st] = *(const half8*)((char*)XT + (st*16 + l15)*512 + (((ks*4+lg) ^ (l15&7)) << 4));
    #pragma unroll
    for (int ct=0; ct<4; ++ct){
      size_t woff = ((size_t)(ks*256 + wid*64 + ct*16 + l15))*32 + lg*8;
      half8 bh = *(const half8*)(whp + woff);
      half8 bl = *(const half8*)(wlp + woff);
      #pragma unroll
      for (int st=0; st<4; ++st){
        if (mode < 2){
          acc[st][ct] = __builtin_amdgcn_mfma_f32_16x16x32_f16(xf[st], bh, acc[st][ct], 0,0,0);
          acc[st][ct] = __builtin_amdgcn_mfma_f32_16x16x32_f16(xf[st], bl, acc[st][ct], 0,0,0);
        } else {
          acc[ct][st] = __builtin_amdgcn_mfma_f32_16x16x32_f16(bh, xf[st], acc[ct][st], 0,0,0);
          acc[ct][st] = __builtin_amdgcn_mfma_f32_16x16x32_f16(bl, xf[st], acc[ct][st], 0,0,0);
        }
      }
    }
  }

  if (mode < 2){
    u16* o = (mode==0 ? qe : kt);
    #pragma unroll
    for (int st=0; st<4; ++st){
      #pragma unroll
      for (int ct=0; ct<4; ++ct){
        int co = wid*64 + ct*16 + l15;
        float bb = bp[co];
        #pragma unroll
        for (int r=0;r<4;r++){
          int sp = sp0 + st*16 + lg*4 + r;
          o[(size_t)(b*N_ + sp)*C_ + co] = f2h(acc[st][ct][r] + bb);
        }
      }
    }
  } else {
    #pragma unroll
    for (int ct=0; ct<4; ++ct){
      #pragma unroll
      for (int st=0; st<4; ++st){
        #pragma unroll
        for (int r=0;r<4;r++){
          int co = wid*64 + ct*16 + lg*4 + r;
          float bb = bp[co];
          se[(size_t)(b*C_ + co)*M_ + sp0 + st*16 + l15] = f2h(acc[ct][st][r] + bb);
        }
      }
    }
  }
}

// ---------------- K3: flash attention, M-split x2, partial outputs ----------------
// 256 thr (4 waves), QB=32, KVB=32, NT=64 iters (one M-half per block).
// Grid 1024, LDS 52KB -> 3 blocks/CU. KT double-buffered; SE single-buffered
// (issued post-B1, retired by counted vmcnt(4) pre-B2; KV is L2-resident via
// XCD swizzle: each XCD owns one (b, half) -> 2MB working set).
__global__ __launch_bounds__(256, 3) void k_attn(
    const u16* __restrict__ qe_g, const u16* __restrict__ kt_g,
    const u16* __restrict__ se_g,
    float* __restrict__ pmean, float* __restrict__ pEs,
    float2* __restrict__ pml)
{
  __shared__ u16 KTs[2][KVB*256];     // 16KB x2, chunk16 ^ (row&7)
  __shared__ u16 SEL[C_*KVB];         // 16KB single, chunk16 ^ ((c>>1)&3)
  __shared__ unsigned WTw[QB*16];     // P weights f16, 32 rows x 64B
  __shared__ float PMX[4][16];
  __shared__ float SRES[QB];
  __shared__ float LRUNS[2][QB];
  __shared__ float MRS[QB];
  __shared__ int FLG[2];

  const int tid = threadIdx.x;
  const int wid = tid >> 6, lane = tid & 63;
  const int l15 = lane & 15, lg = lane >> 4;
  const int qg = wid & 1, mh = wid >> 1;
  // XCD swizzle: wg&7 -> (b, half); consecutive same-XCD blocks = adjacent n-tiles
  const int wg = blockIdx.x;
  const int y = wg & 7, n0t = wg >> 3;
  const int b = y >> 1, half = y & 1;
  const int n0 = n0t * QB;
  const int pidx = y*128 + n0t;

  half8 qf[8];
  {
    const u16* qb = qe_g + ((size_t)(b*N_ + n0 + qg*16 + l15))*C_;
    #pragma unroll
    for (int ks=0; ks<8; ++ks) qf[ks] = *(const half8*)(qb + ks*32 + lg*8);
  }

  int ktsrc[4], sesrc[4];
  #pragma unroll
  for (int i=0;i<4;i++){
    int g = (i*4 + wid)*64 + lane;
    int row = g >> 5, cin = g & 31;
    ktsrc[i] = row*512 + ((cin ^ (row & 7)) << 4);
    int c = g >> 2, mch = (g & 3) ^ ((c >> 1) & 3);
    sesrc[i] = c*8192 + half*4096 + mch*16;
  }
  const char* ktg = (const char*)kt_g + (size_t)b*M_*512 + (size_t)half*2048*512;
  const char* seg = (const char*)se_g + (size_t)b*C_*M_*2;

  float m_run = -1e30f, lrun = 0.f;
  f32x4 accm[2][4], accs[2][4];
  #pragma unroll
  for (int i=0;i<2;i++)
    #pragma unroll
    for (int j=0;j<4;j++){ accm[i][j] = (f32x4)(0.f); accs[i][j] = (f32x4)(0.f); }

  // prologue: KT(0)
  #pragma unroll
  for (int i=0;i<4;i++)
    gll16(ktg + ktsrc[i], (char*)&KTs[0][0] + (i*4 + wid)*1024);

  for (int t=0; t<NT; ++t){
    const int buf = t & 1;
    __syncthreads();     // B1: full drain -> KT(t) ready; SEL + KTs[buf^1] free

    // SE(t) into single buffer (first 4 vm ops)
    {
      int soff = t*64;
      #pragma unroll
      for (int i=0;i<4;i++)
        gll16(seg + soff + sesrc[i], (char*)&SEL[0] + (i*4 + wid)*1024);
    }
    // KT(t+1) prefetch (clamped reload at last iter keeps vmcnt uniform)
    {
      int tn = (t+1 < NT) ? t+1 : t;
      #pragma unroll
      for (int i=0;i<4;i++)
        gll16(ktg + tn*16384 + ktsrc[i], (char*)&KTs[buf^1][0] + (i*4 + wid)*1024);
    }

    // ---- QK^T quadrant: D[m][q], lane q=l15, m = mh*16 + lg*4 + r ----
    f32x4 L0 = (f32x4)(0.f);
    {
      const char* ktb = (const char*)&KTs[buf][0];
      int krow = mh*16 + l15;
      __builtin_amdgcn_s_setprio(1);
      #pragma unroll
      for (int ks=0; ks<8; ++ks){
        half8 a0 = *(const half8*)(ktb + krow*512 + (((ks*4 + lg) ^ (l15 & 7)) << 4));
        L0 = __builtin_amdgcn_mfma_f32_16x16x32_f16(a0, qf[ks], L0, 0,0,0);
      }
      __builtin_amdgcn_s_setprio(0);
    }
    float pm = fmaxf(fmaxf(L0[0], L0[1]), fmaxf(L0[2], L0[3]));
    pm = fmaxf(pm, __shfl_xor(pm, 16));
    pm = fmaxf(pm, __shfl_xor(pm, 32));
    if (lg == 0) PMX[wid][l15] = pm;
    bar_lds();           // Bmax: exchange quadrant maxes (no vmcnt drain)

    float m_tile = fmaxf(pm, PMX[wid ^ 2][l15]);
    int flag = __any(m_tile > m_run + 8.0f);   // defer-max THR=8 (exp2 domain)
    float sv = 1.0f;
    if (flag){
      float mn = fmaxf(m_run, m_tile);
      sv = exp2f(m_run - mn);
      m_run = mn;
    }
    if (mh == 0 && lg == 0) SRES[qg*16 + l15] = sv;
    if (mh == 0 && lane == 0) FLG[qg] = flag;
    unsigned W0 = pkrtz(exp2f(L0[0]-m_run), exp2f(L0[1]-m_run));
    unsigned W1 = pkrtz(exp2f(L0[2]-m_run), exp2f(L0[3]-m_run));
    {
      int row = qg*16 + l15;
      int c16 = (mh*2 + (lg >> 1)) ^ ((l15 >> 1) & 3);
      *(uint2*)((char*)WTw + row*64 + (c16 << 4) + ((lg & 1) << 3)) = make_uint2(W0, W1);
    }
    float rs = sum2(W0) + sum2(W1);
    rs += __shfl_xor(rs, 16);
    rs += __shfl_xor(rs, 32);
    lrun = lrun * sv + rs;

    // B2: retire the 4 SE loads (KT prefetch's 4 stay in flight), then LDS barrier
    asm volatile("s_waitcnt vmcnt(4)" ::: "memory");
    bar_lds();

    if (FLG[0] | FLG[1]){
      #pragma unroll
      for (int rt=0;rt<2;rt++){
        f32x4 s4 = *(const f32x4*)&SRES[rt*16 + lg*4];
        #pragma unroll
        for (int ct=0;ct<4;ct++){
          #pragma unroll
          for (int r=0;r<4;r++){ accm[rt][ct][r] *= s4[r]; accs[rt][ct][r] *= s4[r]; }
        }
      }
    }

    // ---- PV: mean += P*se ; E[s^2] += P*h2 + P*l2 ----
    {
      half8 a[2];
      #pragma unroll
      for (int rt=0;rt<2;rt++){
        int row = rt*16 + l15;
        a[rt] = *(const half8*)((char*)WTw + row*64 + ((lg ^ ((l15>>1)&3)) << 4));
      }
      const char* seb = (const char*)&SEL[0];
      #pragma unroll
      for (int ct=0;ct<4;ct++){
        int c = wid*64 + ct*16 + l15;
        half8 v = *(const half8*)(seb + c*64 + ((lg ^ ((c>>1)&3)) << 4));
        half8 h2, l2;
        sq_hl(v, h2, l2);
        __builtin_amdgcn_s_setprio(1);
        #pragma unroll
        for (int rt=0;rt<2;rt++){
          accm[rt][ct] = __builtin_amdgcn_mfma_f32_16x16x32_f16(a[rt], v,  accm[rt][ct], 0,0,0);
          accs[rt][ct] = __builtin_amdgcn_mfma_f32_16x16x32_f16(a[rt], h2, accs[rt][ct], 0,0,0);
          accs[rt][ct] = __builtin_amdgcn_mfma_f32_16x16x32_f16(a[rt], l2, accs[rt][ct], 0,0,0);
        }
        __builtin_amdgcn_s_setprio(0);
      }
    }
  }

  if (lg == 0) LRUNS[mh][qg*16 + l15] = lrun;
  if (mh == 0 && lg == 0) MRS[qg*16 + l15] = m_run;
  __syncthreads();

  // ---- partial store: normalized mean_h, E[s^2]_h (f32), per-row (m, l) ----
  if (tid < QB){
    float lt = LRUNS[0][tid] + LRUNS[1][tid];
    pml[(size_t)pidx*QB + tid] = make_float2(MRS[tid], lt);
  }
  #pragma unroll
  for (int rt=0;rt<2;rt++){
    f32x4 lv0 = *(const f32x4*)&LRUNS[0][rt*16 + lg*4];
    f32x4 lv1 = *(const f32x4*)&LRUNS[1][rt*16 + lg*4];
    f32x4 inv;
    #pragma unroll
    for (int r=0;r<4;r++) inv[r] = 1.f / (lv0[r] + lv1[r]);
    #pragma unroll
    for (int ct=0;ct<4;ct++){
      int c = wid*64 + ct*16 + l15;
      size_t base = (size_t)pidx*8192 + c*32 + rt*16 + lg*4;
      f32x4 vm, vs;
      #pragma unroll
      for (int r=0;r<4;r++){
        vm[r] = accm[rt][ct][r] * inv[r];
        vs[r] = accs[rt][ct][r] * inv[r];
      }
      *(f32x4*)(pmean + base) = vm;
      *(f32x4*)(pEs   + base) = vs;
    }
  }
}

// ---------------- K4: combine the two M-halves + AdaAttN epilogue ----------------
__global__ __launch_bounds__(256) void k_comb(
    const float* __restrict__ q, const float* __restrict__ stq,
    const float* __restrict__ pmean, const float* __restrict__ pEs,
    const float2* __restrict__ pml, float* __restrict__ out)
{
  const int n0t = blockIdx.x, b = blockIdx.y;
  const int pA = (b*2 + 0)*128 + n0t;
  const int pB = pA + 128;
  const int tid = threadIdx.x, wid = tid >> 6, lane = tid & 63;
  const int hw = lane >> 5, qr = lane & 31;
  const int n0 = n0t * QB;

  float2 A = pml[(size_t)pA*QB + qr];
  float2 Bp = pml[(size_t)pB*QB + qr];
  float m  = fmaxf(A.x, Bp.x);
  float wA = A.y * exp2f(A.x - m);
  float wB = Bp.y * exp2f(Bp.x - m);
  float inv = 1.f / (wA + wB);
  float al = wA * inv, be = wB * inv;

  const float* mA = pmean + (size_t)pA*8192;
  const float* mB = pmean + (size_t)pB*8192;
  const float* sA = pEs   + (size_t)pA*8192;
  const float* sB = pEs   + (size_t)pB*8192;

  #pragma unroll 4
  for (int i=0;i<32;i++){
    int c = i*8 + wid*2 + hw;
    int off = c*32 + qr;
    float mean = al*mA[off] + be*mB[off];
    float Es   = al*sA[off] + be*sB[off];
    float sd   = sqrtf(fmaxf(Es - mean*mean, 0.f));
    float2 st  = *(const float2*)(stq + (size_t)(b*C_ + c)*2);
    size_t gx  = ((size_t)(b*C_ + c))*(size_t)N_ + n0 + qr;
    float qn   = (q[gx] - st.x) * st.y;
    out[gx] = qn * sd + mean;
  }
}

extern "C" void kernel_launch(void* const* d_in, const int* in_sizes, int n_in,
                              void* d_out, int out_size, void* d_ws, size_t ws_size,
                              hipStream_t stream){
  const float* q   = (const float*)d_in[0];
  const float* k   = (const float*)d_in[1];
  const float* wq  = (const float*)d_in[2];
  const float* bq  = (const float*)d_in[3];
  const float* wk  = (const float*)d_in[4];
  const float* bk  = (const float*)d_in[5];
  const float* wsw = (const float*)d_in[6];
  const float* bs  = (const float*)d_in[7];
  float* out = (float*)d_out;

  char* w = (char*)d_ws;
  float* stq = (float*)w;                          // 8KB
  float* stk = (float*)(w + 8192);                 // 8KB
  u16* wh    = (u16*)(w + 16384);                  // 1.125MB
  u16* wl    = (u16*)(w + 16384 + 1179648);        // 1.125MB
  float* bias2 = (float*)(w + 16384 + 2*1179648);  // 9KB -> pad 16KB
  char* big  = w + 16384 + 2*1179648 + 16384;
  u16* qe  = (u16*)big;                            // 8MB
  u16* kt  = qe + (size_t)B_*N_*C_;                // 8MB
  u16* se  = kt + (size_t)B_*M_*C_;                // 8MB
  float* pmean = (float*)(se + (size_t)B_*M_*C_);  // 1024*8192 f32 = 32MB
  float* pEs   = pmean + (size_t)1024*8192;        // 32MB
  float2* pml  = (float2*)(pEs + (size_t)1024*8192); // 256KB

  k_stats<<<dim3(2048), dim3(256), 0, stream>>>(q, k, stq, stk);
  k_wprep<<<dim3(256, 9), dim3(64), 0, stream>>>(wq, bq, wk, bk, wsw, bs,
                                                 stq, stk, wh, wl, bias2);
  k_conv<<<dim3(64, 12), dim3(256), 0, stream>>>(q, k, wh, wl, bias2, qe, kt, se);
  k_attn<<<dim3(1024), dim3(256), 0, stream>>>(qe, kt, se, pmean, pEs, pml);
  k_comb<<<dim3(128, B_), dim3(256), 0, stream>>>(q, stq, pmean, pEs, pml, out);
}

// Round 12
// 257.711 us; speedup vs baseline: 1.1536x; 1.1536x over previous
//
#include <hip/hip_runtime.h>
#include <hip/hip_bf16.h>
#include <cstdint>

typedef unsigned short u16;
typedef __attribute__((ext_vector_type(8))) _Float16 half8;  // 8 f16 in 4 VGPRs
typedef __attribute__((ext_vector_type(2))) __fp16 fp16x2;
typedef __attribute__((ext_vector_type(4))) float f32x4;
typedef __attribute__((ext_vector_type(4))) unsigned u32x4;

#define B_ 4
#define C_ 256
#define N_ 4096
#define M_ 4096
#define QB 32
#define KVB 32
#define NT (M_/KVB)
#define LOG2E 1.44269504088896340736f

__device__ __forceinline__ u16 f2h(float x){
  _Float16 h = (_Float16)x;
  return __builtin_bit_cast(u16, h);
}
__device__ __forceinline__ float h2f(u16 h){
  return (float)__builtin_bit_cast(_Float16, h);
}
__device__ __forceinline__ unsigned pkrtz(float a, float b){
  fp16x2 h = __builtin_amdgcn_cvt_pkrtz(a, b);
  return __builtin_bit_cast(unsigned, h);
}
__device__ __forceinline__ float sum2(unsigned w){
  fp16x2 h = __builtin_bit_cast(fp16x2, w);
  return (float)h.x + (float)h.y;
}
__device__ __forceinline__ void gll16(const void* gsrc, void* ldst){
  __builtin_amdgcn_global_load_lds(
      (const __attribute__((address_space(1))) unsigned int*)gsrc,
      (__attribute__((address_space(3))) unsigned int*)ldst, 16, 0, 0);
}
// LDS-only barrier: does NOT drain vmcnt -> in-flight global_load_lds survives
__device__ __forceinline__ void bar_lds(){
  asm volatile("s_waitcnt lgkmcnt(0)" ::: "memory");
  __builtin_amdgcn_s_barrier();
}
// se^2 hi/lo with guaranteed packed-f16 lowering (residual exact in f16)
__device__ __forceinline__ void sq_hl(half8 v, half8& h2, half8& l2){
  u32x4 vw = __builtin_bit_cast(u32x4, v);
  u32x4 hw, lw;
  #pragma unroll
  for (int j=0;j<4;j++){
    unsigned h, l;
    asm("v_pk_mul_f16 %0, %1, %1" : "=v"(h) : "v"(vw[j]));
    asm("v_pk_fma_f16 %0, %1, %1, %2 neg_lo:[0,0,1] neg_hi:[0,0,1]"
        : "=v"(l) : "v"(vw[j]), "v"(h));
    hw[j] = h; lw[j] = l;
  }
  h2 = __builtin_bit_cast(half8, hw);
  l2 = __builtin_bit_cast(half8, lw);
}

// ---------------- K1: instance-norm stats (mean, rstd) per (b,c) ----------------
__global__ __launch_bounds__(256) void k_stats(const float* __restrict__ q,
                                               const float* __restrict__ k,
                                               float* __restrict__ sq,
                                               float* __restrict__ sk){
  int row = blockIdx.x;
  const float* src = (row < 1024) ? (q + (size_t)row * N_)
                                  : (k + (size_t)(row - 1024) * N_);
  float s = 0.f, ss = 0.f;
  for (int i = threadIdx.x; i < N_/4; i += 256){
    float4 v = ((const float4*)src)[i];
    s  += v.x + v.y + v.z + v.w;
    ss += v.x*v.x + v.y*v.y + v.z*v.z + v.w*v.w;
  }
  #pragma unroll
  for (int off = 32; off >= 1; off >>= 1){
    s  += __shfl_down(s, off);
    ss += __shfl_down(ss, off);
  }
  __shared__ float rs[4], rss[4];
  int w = threadIdx.x >> 6;
  if ((threadIdx.x & 63) == 0){ rs[w] = s; rss[w] = ss; }
  __syncthreads();
  if (threadIdx.x == 0){
    s  = rs[0]+rs[1]+rs[2]+rs[3];
    ss = rss[0]+rss[1]+rss[2]+rss[3];
    float m   = s * (1.f/N_);
    float var = ss * (1.f/N_) - m*m;
    float r   = rsqrtf(fmaxf(var, 0.f) + 1e-5f);
    float* dst = (row < 1024) ? (sq + row*2) : (sk + (row-1024)*2);
    dst[0] = m; dst[1] = r;
  }
}

// ---------------- K1b: fold inorm into weights; f16 hi/lo, frag-major layout ----
__global__ __launch_bounds__(64) void k_wprep(
    const float* __restrict__ wq, const float* __restrict__ bq,
    const float* __restrict__ wk, const float* __restrict__ bk,
    const float* __restrict__ wsw, const float* __restrict__ bs,
    const float* __restrict__ sq, const float* __restrict__ sk,
    u16* __restrict__ wh, u16* __restrict__ wl, float* __restrict__ bias2)
{
  int co = blockIdx.x, z = blockIdx.y;
  int lane = threadIdx.x;
  const float* W; const float* bias; const float* st = nullptr; float sc = 1.f;
  if (z < 4){ W = wq; bias = bq; st = sq + z*512; sc = LOG2E; }
  else if (z < 8){ W = wk; bias = bk; st = sk + (z-4)*512; }
  else { W = wsw; bias = bs; }
  float4 wv = *(const float4*)(W + co*256 + lane*4);
  float w4[4] = {wv.x, wv.y, wv.z, wv.w};
  float vs[4];
  float bsum = 0.f;
  if (st){
    float4 s0 = *(const float4*)(st + lane*8);
    float4 s1 = *(const float4*)(st + lane*8 + 4);
    float mm[4] = {s0.x, s0.z, s1.x, s1.z};
    float rr[4] = {s0.y, s0.w, s1.y, s1.w};
    #pragma unroll
    for (int i=0;i<4;i++){
      vs[i] = w4[i]*rr[i]*sc;
      bsum += w4[i]*rr[i]*mm[i];
    }
  } else {
    #pragma unroll
    for (int i=0;i<4;i++) vs[i] = w4[i];
  }
  u16 hi[4], lo[4];
  #pragma unroll
  for (int i=0;i<4;i++){
    hi[i] = f2h(vs[i]);
    lo[i] = f2h(vs[i] - h2f(hi[i]));
  }
  size_t idx = ((size_t)(z*8 + (lane>>3))*256 + co)*32 + ((lane>>1)&3)*8 + (lane&1)*4;
  *(uint2*)(wh + idx) = make_uint2((unsigned)hi[0] | ((unsigned)hi[1]<<16),
                                   (unsigned)hi[2] | ((unsigned)hi[3]<<16));
  *(uint2*)(wl + idx) = make_uint2((unsigned)lo[0] | ((unsigned)lo[1]<<16),
                                   (unsigned)lo[2] | ((unsigned)lo[3]<<16));
  #pragma unroll
  for (int off = 32; off >= 1; off >>= 1) bsum += __shfl_down(bsum, off);
  if (lane == 0) bias2[z*256 + co] = sc*(bias[co] - bsum);
}

// ---------------- K2: conv1x1 via MFMA (f16 hi/lo weights, raw f16 inputs) ------
__global__ __launch_bounds__(256, 3) void k_conv(
    const float* __restrict__ q, const float* __restrict__ kk,
    const u16* __restrict__ wh, const u16* __restrict__ wl,
    const float* __restrict__ bias2,
    u16* __restrict__ qe, u16* __restrict__ kt, u16* __restrict__ se)
{
  __shared__ u16 XT[64*256];   // 32KB
  const int tid = threadIdx.x;
  const int spt = blockIdx.x, bz = blockIdx.y;
  const int b = bz / 3, mode = bz - b*3;
  const int sp0 = spt*64;
  const float* X = (mode==0 ? q : kk) + (size_t)b*C_*N_;
  const int z = (mode==0) ? b : (mode==1 ? 4+b : 8);
  const u16* whp = wh + (size_t)z*8*256*32;
  const u16* wlp = wl + (size_t)z*8*256*32;
  const float* bp = bias2 + z*256;

  {
    int kc_l = tid & 15, spq = tid >> 4;
    #pragma unroll
    for (int i=0;i<16;i++){
      int kc = i*16 + kc_l;
      float4 v = *(const float4*)(X + (size_t)kc*N_ + sp0 + spq*4);
      float vv[4] = {v.x, v.y, v.z, v.w};
      #pragma unroll
      for (int e=0;e<4;e++){
        int sp = spq*4 + e;
        int byte = sp*512 + (((kc>>3) ^ (sp&7)) << 4) + (kc&7)*2;
        *(u16*)((char*)XT + byte) = f2h(vv[e]);
      }
    }
  }
  __syncthreads();

  const int wid = tid>>6, lane = tid&63, l15 = lane&15, lg = lane>>4;
  f32x4 acc[4][4];
  #pragma unroll
  for (int i=0;i<4;i++)
    #pragma unroll
    for (int j=0;j<4;j++) acc[i][j] = (f32x4)(0.f);

  #pragma unroll
  for (int ks=0; ks<8; ++ks){
    half8 xf[4];
    #pragma unroll
    for (int st=0; st<4; ++st)
      xf[st] = *(const half8*)((char*)XT + (st*16 + l15)*512 + (((ks*4+lg) ^ (l15&7)) << 4));
    #pragma unroll
    for (int ct=0; ct<4; ++ct){
      size_t woff = ((size_t)(ks*256 + wid*64 + ct*16 + l15))*32 + lg*8;
      half8 bh = *(const half8*)(whp + woff);
      half8 bl = *(const half8*)(wlp + woff);
      #pragma unroll
      for (int st=0; st<4; ++st){
        if (mode < 2){
          acc[st][ct] = __builtin_amdgcn_mfma_f32_16x16x32_f16(xf[st], bh, acc[st][ct], 0,0,0);
          acc[st][ct] = __builtin_amdgcn_mfma_f32_16x16x32_f16(xf[st], bl, acc[st][ct], 0,0,0);
        } else {
          acc[ct][st] = __builtin_amdgcn_mfma_f32_16x16x32_f16(bh, xf[st], acc[ct][st], 0,0,0);
          acc[ct][st] = __builtin_amdgcn_mfma_f32_16x16x32_f16(bl, xf[st], acc[ct][st], 0,0,0);
        }
      }
    }
  }

  if (mode < 2){
    u16* o = (mode==0 ? qe : kt);
    #pragma unroll
    for (int st=0; st<4; ++st){
      #pragma unroll
      for (int ct=0; ct<4; ++ct){
        int co = wid*64 + ct*16 + l15;
        float bb = bp[co];
        #pragma unroll
        for (int r=0;r<4;r++){
          int sp = sp0 + st*16 + lg*4 + r;
          o[(size_t)(b*N_ + sp)*C_ + co] = f2h(acc[st][ct][r] + bb);
        }
      }
    }
  } else {
    #pragma unroll
    for (int ct=0; ct<4; ++ct){
      #pragma unroll
      for (int st=0; st<4; ++st){
        #pragma unroll
        for (int r=0;r<4;r++){
          int co = wid*64 + ct*16 + lg*4 + r;
          float bb = bp[co];
          se[(size_t)(b*C_ + co)*M_ + sp0 + st*16 + l15] = f2h(acc[ct][st][r] + bb);
        }
      }
    }
  }
}

// ---------------- K3: swapped-QK flash attention + AdaAttN epilogue ----------------
// Exact R7 structure (236us best): 4 waves, quadrant QK, WT exchange, dbuf KT+SE,
// 3 barriers/iter (B1 full drain, Bmax + B2 LDS-only). Added: XCD swizzle (one
// batch's 4MB KV per XCD-pair -> L2-resident) and setprio around MFMA clusters.
__global__ __launch_bounds__(256, 2) void k_attn(
    const float* __restrict__ q, const float* __restrict__ stq,
    const u16* __restrict__ qe_g, const u16* __restrict__ kt_g,
    const u16* __restrict__ se_g, float* __restrict__ out)
{
  __shared__ u16 KTs[2][KVB*256];     // 16KB x2, chunk16 ^ (row&7)
  __shared__ u16 SEs[2][C_*KVB];      // 16KB x2, chunk16 ^ ((c>>1)&3)
  __shared__ unsigned WTw[QB*16];     // P weights f16, 32 rows x 64B
  __shared__ float PMX[4][16];
  __shared__ float SRES[QB];
  __shared__ float LRUNS[2][QB];
  __shared__ int FLG[2];

  const int tid = threadIdx.x;
  const int wid = tid >> 6, lane = tid & 63;
  const int l15 = lane & 15, lg = lane >> 4;
  const int qg = wid & 1, mh = wid >> 1;
  // XCD-aware bijective swizzle (512 blocks, 8 XCDs): XCD pair <- one batch
  const int wg = blockIdx.x;
  const int sw = (wg & 7)*64 + (wg >> 3);
  const int b = sw >> 7;
  const int n0 = (sw & 127) * QB;

  half8 qf[8];
  {
    const u16* qb = qe_g + ((size_t)(b*N_ + n0 + qg*16 + l15))*C_;
    #pragma unroll
    for (int ks=0; ks<8; ++ks) qf[ks] = *(const half8*)(qb + ks*32 + lg*8);
  }

  int ktsrc[4], sesrc[4];
  #pragma unroll
  for (int i=0;i<4;i++){
    int g = (i*4 + wid)*64 + lane;
    int row = g >> 5, cin = g & 31;
    ktsrc[i] = row*512 + ((cin ^ (row & 7)) << 4);
    int c = g >> 2, mch = (g & 3) ^ ((c >> 1) & 3);
    sesrc[i] = c*8192 + mch*16;
  }
  const char* ktg = (const char*)kt_g + (size_t)b*M_*512;
  const char* seg = (const char*)se_g + (size_t)b*C_*M_*2;

  float m_run = -1e30f, lrun = 0.f;
  f32x4 accm[2][4], accs[2][4];
  #pragma unroll
  for (int i=0;i<2;i++)
    #pragma unroll
    for (int j=0;j<4;j++){ accm[i][j] = (f32x4)(0.f); accs[i][j] = (f32x4)(0.f); }

  // prologue: stage tile 0 into buf 0
  #pragma unroll
  for (int i=0;i<4;i++){
    int o = (i*4 + wid)*1024;
    gll16(ktg + ktsrc[i], (char*)&KTs[0][0] + o);
    gll16(seg + sesrc[i], (char*)&SEs[0][0] + o);
  }

  for (int t=0; t<NT; ++t){
    const int buf = t & 1;
    __syncthreads();     // B1: full drain -> tile(t) staged; all waves past PV(t-1)

    // prefetch tile(t+1); stays in flight across the raw barriers below
    if (t+1 < NT){
      const int nb = buf ^ 1;
      int koff = (t+1)*(KVB*512);
      int soff = (t+1)*(KVB*2);
      #pragma unroll
      for (int i=0;i<4;i++){
        int o = (i*4 + wid)*1024;
        gll16(ktg + koff + ktsrc[i], (char*)&KTs[nb][0] + o);
        gll16(seg + soff + sesrc[i], (char*)&SEs[nb][0] + o);
      }
    }

    // ---- QK^T quadrant: D[m][q], lane q=l15, m = mh*16 + lg*4 + r ----
    f32x4 L0 = (f32x4)(0.f);
    {
      const char* ktb = (const char*)&KTs[buf][0];
      int krow = mh*16 + l15;
      __builtin_amdgcn_s_setprio(1);
      #pragma unroll
      for (int ks=0; ks<8; ++ks){
        half8 a0 = *(const half8*)(ktb + krow*512 + (((ks*4 + lg) ^ (l15 & 7)) << 4));
        L0 = __builtin_amdgcn_mfma_f32_16x16x32_f16(a0, qf[ks], L0, 0,0,0);
      }
      __builtin_amdgcn_s_setprio(0);
    }
    float pm = fmaxf(fmaxf(L0[0], L0[1]), fmaxf(L0[2], L0[3]));
    pm = fmaxf(pm, __shfl_xor(pm, 16));
    pm = fmaxf(pm, __shfl_xor(pm, 32));
    if (lg == 0) PMX[wid][l15] = pm;
    bar_lds();           // Bmax: exchange quadrant maxes (no vmcnt drain)

    float m_tile = fmaxf(pm, PMX[wid ^ 2][l15]);
    int flag = __any(m_tile > m_run + 8.0f);   // defer-max THR=8 (exp2 domain)
    float sv = 1.0f;
    if (flag){
      float mn = fmaxf(m_run, m_tile);
      sv = exp2f(m_run - mn);
      m_run = mn;
    }
    if (mh == 0 && lg == 0) SRES[qg*16 + l15] = sv;
    if (mh == 0 && lane == 0) FLG[qg] = flag;
    unsigned W0 = pkrtz(exp2f(L0[0]-m_run), exp2f(L0[1]-m_run));
    unsigned W1 = pkrtz(exp2f(L0[2]-m_run), exp2f(L0[3]-m_run));
    {
      int row = qg*16 + l15;
      int c16 = (mh*2 + (lg >> 1)) ^ ((l15 >> 1) & 3);
      *(uint2*)((char*)WTw + row*64 + (c16 << 4) + ((lg & 1) << 3)) = make_uint2(W0, W1);
    }
    float rs = sum2(W0) + sum2(W1);            // ROUNDED partial row-sum (own mh)
    rs += __shfl_xor(rs, 16);
    rs += __shfl_xor(rs, 32);
    lrun = lrun * sv + rs;
    bar_lds();           // B2: WT/SRES/FLG ready (no vmcnt drain; prefetch in flight)

    // conditional accumulator rescale (rare after warm-up)
    if (FLG[0] | FLG[1]){
      #pragma unroll
      for (int rt=0;rt<2;rt++){
        f32x4 s4 = *(const f32x4*)&SRES[rt*16 + lg*4];
        #pragma unroll
        for (int ct=0;ct<4;ct++){
          #pragma unroll
          for (int r=0;r<4;r++){ accm[rt][ct][r] *= s4[r]; accs[rt][ct][r] *= s4[r]; }
        }
      }
    }

    // ---- PV: mean += P*se ; E[s^2] += P*h2 + P*l2 (s^2 hi/lo in-register) ----
    {
      half8 a[2];
      #pragma unroll
      for (int rt=0;rt<2;rt++){
        int row = rt*16 + l15;
        a[rt] = *(const half8*)((char*)WTw + row*64 + ((lg ^ ((l15>>1)&3)) << 4));
      }
      const char* seb = (const char*)&SEs[buf][0];
      #pragma unroll
      for (int ct=0;ct<4;ct++){
        int c = wid*64 + ct*16 + l15;
        half8 v = *(const half8*)(seb + c*64 + ((lg ^ ((c>>1)&3)) << 4));
        half8 h2, l2;
        sq_hl(v, h2, l2);
        __builtin_amdgcn_s_setprio(1);
        #pragma unroll
        for (int rt=0;rt<2;rt++){
          accm[rt][ct] = __builtin_amdgcn_mfma_f32_16x16x32_f16(a[rt], v,  accm[rt][ct], 0,0,0);
          accs[rt][ct] = __builtin_amdgcn_mfma_f32_16x16x32_f16(a[rt], h2, accs[rt][ct], 0,0,0);
          accs[rt][ct] = __builtin_amdgcn_mfma_f32_16x16x32_f16(a[rt], l2, accs[rt][ct], 0,0,0);
        }
        __builtin_amdgcn_s_setprio(0);
      }
    }
  }

  if (lg == 0) LRUNS[mh][qg*16 + l15] = lrun;
  __syncthreads();

  // ---- epilogue: combine l, normalize, var=relu(E[s^2]-mean^2), cs = qn*std + mean ----
  #pragma unroll
  for (int rt=0;rt<2;rt++){
    f32x4 lv0 = *(const f32x4*)&LRUNS[0][rt*16 + lg*4];
    f32x4 lv1 = *(const f32x4*)&LRUNS[1][rt*16 + lg*4];
    f32x4 inv;
    #pragma unroll
    for (int r=0;r<4;r++) inv[r] = 1.f / (lv0[r] + lv1[r]);
    #pragma unroll
    for (int ct=0;ct<4;ct++){
      int c = wid*64 + ct*16 + l15;
      float2 st = *(const float2*)(stq + (size_t)(b*C_ + c)*2);
      size_t base = ((size_t)(b*C_ + c))*(size_t)N_ + (size_t)(n0 + rt*16 + lg*4);
      f32x4 qv = *(const f32x4*)(q + base);
      f32x4 res;
      #pragma unroll
      for (int r=0;r<4;r++){
        float mean = accm[rt][ct][r] * inv[r];
        float ms   = accs[rt][ct][r] * inv[r];
        float sd   = sqrtf(fmaxf(ms - mean*mean, 0.f));
        float qn   = (qv[r] - st.x) * st.y;
        res[r] = qn * sd + mean;
      }
      *(f32x4*)(out + base) = res;
    }
  }
}

extern "C" void kernel_launch(void* const* d_in, const int* in_sizes, int n_in,
                              void* d_out, int out_size, void* d_ws, size_t ws_size,
                              hipStream_t stream){
  const float* q   = (const float*)d_in[0];
  const float* k   = (const float*)d_in[1];
  const float* wq  = (const float*)d_in[2];
  const float* bq  = (const float*)d_in[3];
  const float* wk  = (const float*)d_in[4];
  const float* bk  = (const float*)d_in[5];
  const float* wsw = (const float*)d_in[6];
  const float* bs  = (const float*)d_in[7];
  float* out = (float*)d_out;

  char* w = (char*)d_ws;
  float* stq = (float*)w;                          // 8KB
  float* stk = (float*)(w + 8192);                 // 8KB
  u16* wh    = (u16*)(w + 16384);                  // 1.125MB
  u16* wl    = (u16*)(w + 16384 + 1179648);        // 1.125MB
  float* bias2 = (float*)(w + 16384 + 2*1179648);  // 9KB -> pad 16KB
  char* big  = w + 16384 + 2*1179648 + 16384;
  u16* qe  = (u16*)big;                            // 8MB
  u16* kt  = qe + (size_t)B_*N_*C_;                // 8MB
  u16* se  = kt + (size_t)B_*M_*C_;                // 8MB

  k_stats<<<dim3(2048), dim3(256), 0, stream>>>(q, k, stq, stk);
  k_wprep<<<dim3(256, 9), dim3(64), 0, stream>>>(wq, bq, wk, bk, wsw, bs,
                                                 stq, stk, wh, wl, bias2);
  k_conv<<<dim3(64, 12), dim3(256), 0, stream>>>(q, k, wh, wl, bias2, qe, kt, se);
  k_attn<<<dim3(512), dim3(256), 0, stream>>>(q, stq, qe, kt, se, out);
}

// Round 13
// 242.603 us; speedup vs baseline: 1.2254x; 1.0623x over previous
//
#include <hip/hip_runtime.h>
#include <hip/hip_bf16.h>
#include <cstdint>

typedef unsigned short u16;
typedef __attribute__((ext_vector_type(8))) _Float16 half8;  // 8 f16 in 4 VGPRs
typedef __attribute__((ext_vector_type(2))) __fp16 fp16x2;
typedef __attribute__((ext_vector_type(4))) float f32x4;
typedef __attribute__((ext_vector_type(4))) unsigned u32x4;

#define B_ 4
#define C_ 256
#define N_ 4096
#define M_ 4096
#define QB 32
#define KVB 32
#define NT (M_/KVB)
#define LOG2E 1.44269504088896340736f

__device__ __forceinline__ u16 f2h(float x){
  _Float16 h = (_Float16)x;
  return __builtin_bit_cast(u16, h);
}
__device__ __forceinline__ float h2f(u16 h){
  return (float)__builtin_bit_cast(_Float16, h);
}
__device__ __forceinline__ unsigned pkrtz(float a, float b){
  fp16x2 h = __builtin_amdgcn_cvt_pkrtz(a, b);
  return __builtin_bit_cast(unsigned, h);
}
__device__ __forceinline__ float sum2(unsigned w){
  fp16x2 h = __builtin_bit_cast(fp16x2, w);
  return (float)h.x + (float)h.y;
}
__device__ __forceinline__ void gll16(const void* gsrc, void* ldst){
  __builtin_amdgcn_global_load_lds(
      (const __attribute__((address_space(1))) unsigned int*)gsrc,
      (__attribute__((address_space(3))) unsigned int*)ldst, 16, 0, 0);
}
// LDS-only barrier: does NOT drain vmcnt -> in-flight global_load_lds survives
__device__ __forceinline__ void bar_lds(){
  asm volatile("s_waitcnt lgkmcnt(0)" ::: "memory");
  __builtin_amdgcn_s_barrier();
}
// se^2 hi/lo with guaranteed packed-f16 lowering (residual exact in f16)
__device__ __forceinline__ void sq_hl(half8 v, half8& h2, half8& l2){
  u32x4 vw = __builtin_bit_cast(u32x4, v);
  u32x4 hw, lw;
  #pragma unroll
  for (int j=0;j<4;j++){
    unsigned h, l;
    asm("v_pk_mul_f16 %0, %1, %1" : "=v"(h) : "v"(vw[j]));
    asm("v_pk_fma_f16 %0, %1, %1, %2 neg_lo:[0,0,1] neg_hi:[0,0,1]"
        : "=v"(l) : "v"(vw[j]), "v"(h));
    hw[j] = h; lw[j] = l;
  }
  h2 = __builtin_bit_cast(half8, hw);
  l2 = __builtin_bit_cast(half8, lw);
}

// ---------------- K1: instance-norm stats (mean, rstd) per (b,c) ----------------
__global__ __launch_bounds__(256) void k_stats(const float* __restrict__ q,
                                               const float* __restrict__ k,
                                               float* __restrict__ sq,
                                               float* __restrict__ sk){
  int row = blockIdx.x;
  const float* src = (row < 1024) ? (q + (size_t)row * N_)
                                  : (k + (size_t)(row - 1024) * N_);
  float s = 0.f, ss = 0.f;
  for (int i = threadIdx.x; i < N_/4; i += 256){
    float4 v = ((const float4*)src)[i];
    s  += v.x + v.y + v.z + v.w;
    ss += v.x*v.x + v.y*v.y + v.z*v.z + v.w*v.w;
  }
  #pragma unroll
  for (int off = 32; off >= 1; off >>= 1){
    s  += __shfl_down(s, off);
    ss += __shfl_down(ss, off);
  }
  __shared__ float rs[4], rss[4];
  int w = threadIdx.x >> 6;
  if ((threadIdx.x & 63) == 0){ rs[w] = s; rss[w] = ss; }
  __syncthreads();
  if (threadIdx.x == 0){
    s  = rs[0]+rs[1]+rs[2]+rs[3];
    ss = rss[0]+rss[1]+rss[2]+rss[3];
    float m   = s * (1.f/N_);
    float var = ss * (1.f/N_) - m*m;
    float r   = rsqrtf(fmaxf(var, 0.f) + 1e-5f);
    float* dst = (row < 1024) ? (sq + row*2) : (sk + (row-1024)*2);
    dst[0] = m; dst[1] = r;
  }
}

// ---------------- K1b: fold inorm into weights; f16 hi/lo, frag-major layout ----
__global__ __launch_bounds__(64) void k_wprep(
    const float* __restrict__ wq, const float* __restrict__ bq,
    const float* __restrict__ wk, const float* __restrict__ bk,
    const float* __restrict__ wsw, const float* __restrict__ bs,
    const float* __restrict__ sq, const float* __restrict__ sk,
    u16* __restrict__ wh, u16* __restrict__ wl, float* __restrict__ bias2)
{
  int co = blockIdx.x, z = blockIdx.y;
  int lane = threadIdx.x;
  const float* W; const float* bias; const float* st = nullptr; float sc = 1.f;
  if (z < 4){ W = wq; bias = bq; st = sq + z*512; sc = LOG2E; }
  else if (z < 8){ W = wk; bias = bk; st = sk + (z-4)*512; }
  else { W = wsw; bias = bs; }
  float4 wv = *(const float4*)(W + co*256 + lane*4);
  float w4[4] = {wv.x, wv.y, wv.z, wv.w};
  float vs[4];
  float bsum = 0.f;
  if (st){
    float4 s0 = *(const float4*)(st + lane*8);
    float4 s1 = *(const float4*)(st + lane*8 + 4);
    float mm[4] = {s0.x, s0.z, s1.x, s1.z};
    float rr[4] = {s0.y, s0.w, s1.y, s1.w};
    #pragma unroll
    for (int i=0;i<4;i++){
      vs[i] = w4[i]*rr[i]*sc;
      bsum += w4[i]*rr[i]*mm[i];
    }
  } else {
    #pragma unroll
    for (int i=0;i<4;i++) vs[i] = w4[i];
  }
  u16 hi[4], lo[4];
  #pragma unroll
  for (int i=0;i<4;i++){
    hi[i] = f2h(vs[i]);
    lo[i] = f2h(vs[i] - h2f(hi[i]));
  }
  size_t idx = ((size_t)(z*8 + (lane>>3))*256 + co)*32 + ((lane>>1)&3)*8 + (lane&1)*4;
  *(uint2*)(wh + idx) = make_uint2((unsigned)hi[0] | ((unsigned)hi[1]<<16),
                                   (unsigned)hi[2] | ((unsigned)hi[3]<<16));
  *(uint2*)(wl + idx) = make_uint2((unsigned)lo[0] | ((unsigned)lo[1]<<16),
                                   (unsigned)lo[2] | ((unsigned)lo[3]<<16));
  #pragma unroll
  for (int off = 32; off >= 1; off >>= 1) bsum += __shfl_down(bsum, off);
  if (lane == 0) bias2[z*256 + co] = sc*(bias[co] - bsum);
}

// ---------------- K2: conv1x1 via MFMA (f16 hi/lo weights, raw f16 inputs) ------
__global__ __launch_bounds__(256, 3) void k_conv(
    const float* __restrict__ q, const float* __restrict__ kk,
    const u16* __restrict__ wh, const u16* __restrict__ wl,
    const float* __restrict__ bias2,
    u16* __restrict__ qe, u16* __restrict__ kt, u16* __restrict__ se)
{
  __shared__ u16 XT[64*256];   // 32KB
  const int tid = threadIdx.x;
  const int spt = blockIdx.x, bz = blockIdx.y;
  const int b = bz / 3, mode = bz - b*3;
  const int sp0 = spt*64;
  const float* X = (mode==0 ? q : kk) + (size_t)b*C_*N_;
  const int z = (mode==0) ? b : (mode==1 ? 4+b : 8);
  const u16* whp = wh + (size_t)z*8*256*32;
  const u16* wlp = wl + (size_t)z*8*256*32;
  const float* bp = bias2 + z*256;

  {
    int kc_l = tid & 15, spq = tid >> 4;
    #pragma unroll
    for (int i=0;i<16;i++){
      int kc = i*16 + kc_l;
      float4 v = *(const float4*)(X + (size_t)kc*N_ + sp0 + spq*4);
      float vv[4] = {v.x, v.y, v.z, v.w};
      #pragma unroll
      for (int e=0;e<4;e++){
        int sp = spq*4 + e;
        int byte = sp*512 + (((kc>>3) ^ (sp&7)) << 4) + (kc&7)*2;
        *(u16*)((char*)XT + byte) = f2h(vv[e]);
      }
    }
  }
  __syncthreads();

  const int wid = tid>>6, lane = tid&63, l15 = lane&15, lg = lane>>4;
  f32x4 acc[4][4];
  #pragma unroll
  for (int i=0;i<4;i++)
    #pragma unroll
    for (int j=0;j<4;j++) acc[i][j] = (f32x4)(0.f);

  #pragma unroll
  for (int ks=0; ks<8; ++ks){
    half8 xf[4];
    #pragma unroll
    for (int st=0; st<4; ++st)
      xf[st] = *(const half8*)((char*)XT + (st*16 + l15)*512 + (((ks*4+lg) ^ (l15&7)) << 4));
    #pragma unroll
    for (int ct=0; ct<4; ++ct){
      size_t woff = ((size_t)(ks*256 + wid*64 + ct*16 + l15))*32 + lg*8;
      half8 bh = *(const half8*)(whp + woff);
      half8 bl = *(const half8*)(wlp + woff);
      #pragma unroll
      for (int st=0; st<4; ++st){
        if (mode < 2){
          acc[st][ct] = __builtin_amdgcn_mfma_f32_16x16x32_f16(xf[st], bh, acc[st][ct], 0,0,0);
          acc[st][ct] = __builtin_amdgcn_mfma_f32_16x16x32_f16(xf[st], bl, acc[st][ct], 0,0,0);
        } else {
          acc[ct][st] = __builtin_amdgcn_mfma_f32_16x16x32_f16(bh, xf[st], acc[ct][st], 0,0,0);
          acc[ct][st] = __builtin_amdgcn_mfma_f32_16x16x32_f16(bl, xf[st], acc[ct][st], 0,0,0);
        }
      }
    }
  }

  if (mode < 2){
    u16* o = (mode==0 ? qe : kt);
    #pragma unroll
    for (int st=0; st<4; ++st){
      #pragma unroll
      for (int ct=0; ct<4; ++ct){
        int co = wid*64 + ct*16 + l15;
        float bb = bp[co];
        #pragma unroll
        for (int r=0;r<4;r++){
          int sp = sp0 + st*16 + lg*4 + r;
          o[(size_t)(b*N_ + sp)*C_ + co] = f2h(acc[st][ct][r] + bb);
        }
      }
    }
  } else {
    #pragma unroll
    for (int ct=0; ct<4; ++ct){
      #pragma unroll
      for (int st=0; st<4; ++st){
        #pragma unroll
        for (int r=0;r<4;r++){
          int co = wid*64 + ct*16 + lg*4 + r;
          float bb = bp[co];
          se[(size_t)(b*C_ + co)*M_ + sp0 + st*16 + l15] = f2h(acc[ct][st][r] + bb);
        }
      }
    }
  }
}

// ---------------- K3: swapped-QK flash attention + AdaAttN epilogue ----------------
// R7 structure (best passing): 4 waves, quadrant QK, WT exchange, dbuf KT+SE,
// B1 full drain + Bmax/B2 LDS-only. This round: XCD swizzle kept, setprio removed,
// QK MFMA chain split 8->4+4, E[s^2] l2-stream gets its own accumulator (all PV
// MFMAs independent) -> shorter latency chains in the latency-bound regime.
__global__ __launch_bounds__(256, 2) void k_attn(
    const float* __restrict__ q, const float* __restrict__ stq,
    const u16* __restrict__ qe_g, const u16* __restrict__ kt_g,
    const u16* __restrict__ se_g, float* __restrict__ out)
{
  __shared__ u16 KTs[2][KVB*256];     // 16KB x2, chunk16 ^ (row&7)
  __shared__ u16 SEs[2][C_*KVB];      // 16KB x2, chunk16 ^ ((c>>1)&3)
  __shared__ unsigned WTw[QB*16];     // P weights f16, 32 rows x 64B
  __shared__ float PMX[4][16];
  __shared__ float SRES[QB];
  __shared__ float LRUNS[2][QB];
  __shared__ int FLG[2];

  const int tid = threadIdx.x;
  const int wid = tid >> 6, lane = tid & 63;
  const int l15 = lane & 15, lg = lane >> 4;
  const int qg = wid & 1, mh = wid >> 1;
  // XCD-aware bijective swizzle (512 blocks, 8 XCDs): XCD pair <- one batch
  const int wg = blockIdx.x;
  const int sw = (wg & 7)*64 + (wg >> 3);
  const int b = sw >> 7;
  const int n0 = (sw & 127) * QB;

  half8 qf[8];
  {
    const u16* qb = qe_g + ((size_t)(b*N_ + n0 + qg*16 + l15))*C_;
    #pragma unroll
    for (int ks=0; ks<8; ++ks) qf[ks] = *(const half8*)(qb + ks*32 + lg*8);
  }

  int ktsrc[4], sesrc[4];
  #pragma unroll
  for (int i=0;i<4;i++){
    int g = (i*4 + wid)*64 + lane;
    int row = g >> 5, cin = g & 31;
    ktsrc[i] = row*512 + ((cin ^ (row & 7)) << 4);
    int c = g >> 2, mch = (g & 3) ^ ((c >> 1) & 3);
    sesrc[i] = c*8192 + mch*16;
  }
  const char* ktg = (const char*)kt_g + (size_t)b*M_*512;
  const char* seg = (const char*)se_g + (size_t)b*C_*M_*2;

  float m_run = -1e30f, lrun = 0.f;
  f32x4 accm[2][4], accs[2][4], accs2[2][4];
  #pragma unroll
  for (int i=0;i<2;i++)
    #pragma unroll
    for (int j=0;j<4;j++){
      accm[i][j] = (f32x4)(0.f); accs[i][j] = (f32x4)(0.f); accs2[i][j] = (f32x4)(0.f);
    }

  // prologue: stage tile 0 into buf 0
  #pragma unroll
  for (int i=0;i<4;i++){
    int o = (i*4 + wid)*1024;
    gll16(ktg + ktsrc[i], (char*)&KTs[0][0] + o);
    gll16(seg + sesrc[i], (char*)&SEs[0][0] + o);
  }

  for (int t=0; t<NT; ++t){
    const int buf = t & 1;
    __syncthreads();     // B1: full drain -> tile(t) staged; all waves past PV(t-1)

    // prefetch tile(t+1); stays in flight across the raw barriers below
    if (t+1 < NT){
      const int nb = buf ^ 1;
      int koff = (t+1)*(KVB*512);
      int soff = (t+1)*(KVB*2);
      #pragma unroll
      for (int i=0;i<4;i++){
        int o = (i*4 + wid)*1024;
        gll16(ktg + koff + ktsrc[i], (char*)&KTs[nb][0] + o);
        gll16(seg + soff + sesrc[i], (char*)&SEs[nb][0] + o);
      }
    }

    // ---- QK^T quadrant: D[m][q]; two independent 4-chains, summed ----
    f32x4 L0;
    {
      const char* ktb = (const char*)&KTs[buf][0];
      int krow = mh*16 + l15;
      f32x4 LA = (f32x4)(0.f), LB = (f32x4)(0.f);
      #pragma unroll
      for (int ks=0; ks<4; ++ks){
        half8 a0 = *(const half8*)(ktb + krow*512 + (((ks*4 + lg) ^ (l15 & 7)) << 4));
        half8 a1 = *(const half8*)(ktb + krow*512 + ((((ks+4)*4 + lg) ^ (l15 & 7)) << 4));
        LA = __builtin_amdgcn_mfma_f32_16x16x32_f16(a0, qf[ks],   LA, 0,0,0);
        LB = __builtin_amdgcn_mfma_f32_16x16x32_f16(a1, qf[ks+4], LB, 0,0,0);
      }
      #pragma unroll
      for (int r=0;r<4;r++) L0[r] = LA[r] + LB[r];
    }
    float pm = fmaxf(fmaxf(L0[0], L0[1]), fmaxf(L0[2], L0[3]));
    pm = fmaxf(pm, __shfl_xor(pm, 16));
    pm = fmaxf(pm, __shfl_xor(pm, 32));
    if (lg == 0) PMX[wid][l15] = pm;
    bar_lds();           // Bmax: exchange quadrant maxes (no vmcnt drain)

    float m_tile = fmaxf(pm, PMX[wid ^ 2][l15]);
    int flag = __any(m_tile > m_run + 8.0f);   // defer-max THR=8 (exp2 domain)
    float sv = 1.0f;
    if (flag){
      float mn = fmaxf(m_run, m_tile);
      sv = exp2f(m_run - mn);
      m_run = mn;
    }
    if (mh == 0 && lg == 0) SRES[qg*16 + l15] = sv;
    if (mh == 0 && lane == 0) FLG[qg] = flag;
    unsigned W0 = pkrtz(exp2f(L0[0]-m_run), exp2f(L0[1]-m_run));
    unsigned W1 = pkrtz(exp2f(L0[2]-m_run), exp2f(L0[3]-m_run));
    {
      int row = qg*16 + l15;
      int c16 = (mh*2 + (lg >> 1)) ^ ((l15 >> 1) & 3);
      *(uint2*)((char*)WTw + row*64 + (c16 << 4) + ((lg & 1) << 3)) = make_uint2(W0, W1);
    }
    float rs = sum2(W0) + sum2(W1);            // ROUNDED partial row-sum (own mh)
    rs += __shfl_xor(rs, 16);
    rs += __shfl_xor(rs, 32);
    lrun = lrun * sv + rs;
    bar_lds();           // B2: WT/SRES/FLG ready (no vmcnt drain; prefetch in flight)

    // conditional accumulator rescale (rare after warm-up)
    if (FLG[0] | FLG[1]){
      #pragma unroll
      for (int rt=0;rt<2;rt++){
        f32x4 s4 = *(const f32x4*)&SRES[rt*16 + lg*4];
        #pragma unroll
        for (int ct=0;ct<4;ct++){
          #pragma unroll
          for (int r=0;r<4;r++){
            accm[rt][ct][r] *= s4[r]; accs[rt][ct][r] *= s4[r]; accs2[rt][ct][r] *= s4[r];
          }
        }
      }
    }

    // ---- PV: all 6 MFMAs per ct independent (accm / accs / accs2 streams) ----
    {
      half8 a[2];
      #pragma unroll
      for (int rt=0;rt<2;rt++){
        int row = rt*16 + l15;
        a[rt] = *(const half8*)((char*)WTw + row*64 + ((lg ^ ((l15>>1)&3)) << 4));
      }
      const char* seb = (const char*)&SEs[buf][0];
      #pragma unroll
      for (int ct=0;ct<4;ct++){
        int c = wid*64 + ct*16 + l15;
        half8 v = *(const half8*)(seb + c*64 + ((lg ^ ((c>>1)&3)) << 4));
        half8 h2, l2;
        sq_hl(v, h2, l2);
        #pragma unroll
        for (int rt=0;rt<2;rt++){
          accm[rt][ct]  = __builtin_amdgcn_mfma_f32_16x16x32_f16(a[rt], v,  accm[rt][ct],  0,0,0);
          accs[rt][ct]  = __builtin_amdgcn_mfma_f32_16x16x32_f16(a[rt], h2, accs[rt][ct],  0,0,0);
          accs2[rt][ct] = __builtin_amdgcn_mfma_f32_16x16x32_f16(a[rt], l2, accs2[rt][ct], 0,0,0);
        }
      }
    }
  }

  if (lg == 0) LRUNS[mh][qg*16 + l15] = lrun;
  __syncthreads();

  // ---- epilogue: combine l, normalize, var=relu(E[s^2]-mean^2), cs = qn*std + mean ----
  #pragma unroll
  for (int rt=0;rt<2;rt++){
    f32x4 lv0 = *(const f32x4*)&LRUNS[0][rt*16 + lg*4];
    f32x4 lv1 = *(const f32x4*)&LRUNS[1][rt*16 + lg*4];
    f32x4 inv;
    #pragma unroll
    for (int r=0;r<4;r++) inv[r] = 1.f / (lv0[r] + lv1[r]);
    #pragma unroll
    for (int ct=0;ct<4;ct++){
      int c = wid*64 + ct*16 + l15;
      float2 st = *(const float2*)(stq + (size_t)(b*C_ + c)*2);
      size_t base = ((size_t)(b*C_ + c))*(size_t)N_ + (size_t)(n0 + rt*16 + lg*4);
      f32x4 qv = *(const f32x4*)(q + base);
      f32x4 res;
      #pragma unroll
      for (int r=0;r<4;r++){
        float mean = accm[rt][ct][r] * inv[r];
        float ms   = (accs[rt][ct][r] + accs2[rt][ct][r]) * inv[r];
        float sd   = sqrtf(fmaxf(ms - mean*mean, 0.f));
        float qn   = (qv[r] - st.x) * st.y;
        res[r] = qn * sd + mean;
      }
      *(f32x4*)(out + base) = res;
    }
  }
}

extern "C" void kernel_launch(void* const* d_in, const int* in_sizes, int n_in,
                              void* d_out, int out_size, void* d_ws, size_t ws_size,
                              hipStream_t stream){
  const float* q   = (const float*)d_in[0];
  const float* k   = (const float*)d_in[1];
  const float* wq  = (const float*)d_in[2];
  const float* bq  = (const float*)d_in[3];
  const float* wk  = (const float*)d_in[4];
  const float* bk  = (const float*)d_in[5];
  const float* wsw = (const float*)d_in[6];
  const float* bs  = (const float*)d_in[7];
  float* out = (float*)d_out;

  char* w = (char*)d_ws;
  float* stq = (float*)w;                          // 8KB
  float* stk = (float*)(w + 8192);                 // 8KB
  u16* wh    = (u16*)(w + 16384);                  // 1.125MB
  u16* wl    = (u16*)(w + 16384 + 1179648);        // 1.125MB
  float* bias2 = (float*)(w + 16384 + 2*1179648);  // 9KB -> pad 16KB
  char* big  = w + 16384 + 2*1179648 + 16384;
  u16* qe  = (u16*)big;                            // 8MB
  u16* kt  = qe + (size_t)B_*N_*C_;                // 8MB
  u16* se  = kt + (size_t)B_*M_*C_;                // 8MB

  k_stats<<<dim3(2048), dim3(256), 0, stream>>>(q, k, stq, stk);
  k_wprep<<<dim3(256, 9), dim3(64), 0, stream>>>(wq, bq, wk, bk, wsw, bs,
                                                 stq, stk, wh, wl, bias2);
  k_conv<<<dim3(64, 12), dim3(256), 0, stream>>>(q, k, wh, wl, bias2, qe, kt, se);
  k_attn<<<dim3(512), dim3(256), 0, stream>>>(q, stq, qe, kt, se, out);
}

// Round 16
// 242.422 us; speedup vs baseline: 1.2263x; 1.0007x over previous
//
#include <hip/hip_runtime.h>
#include <hip/hip_bf16.h>
#include <cstdint>

typedef unsigned short u16;
typedef __attribute__((ext_vector_type(8))) _Float16 half8;  // 8 f16 in 4 VGPRs
typedef __attribute__((ext_vector_type(2))) __fp16 fp16x2;
typedef __attribute__((ext_vector_type(4))) float f32x4;
typedef __attribute__((ext_vector_type(4))) unsigned u32x4;

#define B_ 4
#define C_ 256
#define N_ 4096
#define M_ 4096
#define QB 32
#define KVB 32
#define NT (M_/KVB)
#define LOG2E 1.44269504088896340736f

__device__ __forceinline__ u16 f2h(float x){
  _Float16 h = (_Float16)x;
  return __builtin_bit_cast(u16, h);
}
__device__ __forceinline__ float h2f(u16 h){
  return (float)__builtin_bit_cast(_Float16, h);
}
__device__ __forceinline__ unsigned pkrtz(float a, float b){
  fp16x2 h = __builtin_amdgcn_cvt_pkrtz(a, b);
  return __builtin_bit_cast(unsigned, h);
}
__device__ __forceinline__ float sum2(unsigned w){
  fp16x2 h = __builtin_bit_cast(fp16x2, w);
  return (float)h.x + (float)h.y;
}
__device__ __forceinline__ void gll16(const void* gsrc, void* ldst){
  __builtin_amdgcn_global_load_lds(
      (const __attribute__((address_space(1))) unsigned int*)gsrc,
      (__attribute__((address_space(3))) unsigned int*)ldst, 16, 0, 0);
}
// LDS-only barrier: does NOT drain vmcnt -> in-flight global_load_lds survives
__device__ __forceinline__ void bar_lds(){
  asm volatile("s_waitcnt lgkmcnt(0)" ::: "memory");
  __builtin_amdgcn_s_barrier();
}
// se^2 hi/lo with guaranteed packed-f16 lowering (residual exact in f16)
__device__ __forceinline__ void sq_hl(half8 v, half8& h2, half8& l2){
  u32x4 vw = __builtin_bit_cast(u32x4, v);
  u32x4 hw, lw;
  #pragma unroll
  for (int j=0;j<4;j++){
    unsigned h, l;
    asm("v_pk_mul_f16 %0, %1, %1" : "=v"(h) : "v"(vw[j]));
    asm("v_pk_fma_f16 %0, %1, %1, %2 neg_lo:[0,0,1] neg_hi:[0,0,1]"
        : "=v"(l) : "v"(vw[j]), "v"(h));
    hw[j] = h; lw[j] = l;
  }
  h2 = __builtin_bit_cast(half8, hw);
  l2 = __builtin_bit_cast(half8, lw);
}

// ---------------- K1: instance-norm stats (mean, rstd) per (b,c) ----------------
__global__ __launch_bounds__(256) void k_stats(const float* __restrict__ q,
                                               const float* __restrict__ k,
                                               float* __restrict__ sq,
                                               float* __restrict__ sk){
  int row = blockIdx.x;
  const float* src = (row < 1024) ? (q + (size_t)row * N_)
                                  : (k + (size_t)(row - 1024) * N_);
  float s = 0.f, ss = 0.f;
  for (int i = threadIdx.x; i < N_/4; i += 256){
    float4 v = ((const float4*)src)[i];
    s  += v.x + v.y + v.z + v.w;
    ss += v.x*v.x + v.y*v.y + v.z*v.z + v.w*v.w;
  }
  #pragma unroll
  for (int off = 32; off >= 1; off >>= 1){
    s  += __shfl_down(s, off);
    ss += __shfl_down(ss, off);
  }
  __shared__ float rs[4], rss[4];
  int w = threadIdx.x >> 6;
  if ((threadIdx.x & 63) == 0){ rs[w] = s; rss[w] = ss; }
  __syncthreads();
  if (threadIdx.x == 0){
    s  = rs[0]+rs[1]+rs[2]+rs[3];
    ss = rss[0]+rss[1]+rss[2]+rss[3];
    float m   = s * (1.f/N_);
    float var = ss * (1.f/N_) - m*m;
    float r   = rsqrtf(fmaxf(var, 0.f) + 1e-5f);
    float* dst = (row < 1024) ? (sq + row*2) : (sk + (row-1024)*2);
    dst[0] = m; dst[1] = r;
  }
}

// ---------------- K1b: fold inorm into weights; f16 hi/lo, frag-major layout ----
__global__ __launch_bounds__(64) void k_wprep(
    const float* __restrict__ wq, const float* __restrict__ bq,
    const float* __restrict__ wk, const float* __restrict__ bk,
    const float* __restrict__ wsw, const float* __restrict__ bs,
    const float* __restrict__ sq, const float* __restrict__ sk,
    u16* __restrict__ wh, u16* __restrict__ wl, float* __restrict__ bias2)
{
  int co = blockIdx.x, z = blockIdx.y;
  int lane = threadIdx.x;
  const float* W; const float* bias; const float* st = nullptr; float sc = 1.f;
  if (z < 4){ W = wq; bias = bq; st = sq + z*512; sc = LOG2E; }
  else if (z < 8){ W = wk; bias = bk; st = sk + (z-4)*512; }
  else { W = wsw; bias = bs; }
  float4 wv = *(const float4*)(W + co*256 + lane*4);
  float w4[4] = {wv.x, wv.y, wv.z, wv.w};
  float vs[4];
  float bsum = 0.f;
  if (st){
    float4 s0 = *(const float4*)(st + lane*8);
    float4 s1 = *(const float4*)(st + lane*8 + 4);
    float mm[4] = {s0.x, s0.z, s1.x, s1.z};
    float rr[4] = {s0.y, s0.w, s1.y, s1.w};
    #pragma unroll
    for (int i=0;i<4;i++){
      vs[i] = w4[i]*rr[i]*sc;
      bsum += w4[i]*rr[i]*mm[i];
    }
  } else {
    #pragma unroll
    for (int i=0;i<4;i++) vs[i] = w4[i];
  }
  u16 hi[4], lo[4];
  #pragma unroll
  for (int i=0;i<4;i++){
    hi[i] = f2h(vs[i]);
    lo[i] = f2h(vs[i] - h2f(hi[i]));
  }
  size_t idx = ((size_t)(z*8 + (lane>>3))*256 + co)*32 + ((lane>>1)&3)*8 + (lane&1)*4;
  *(uint2*)(wh + idx) = make_uint2((unsigned)hi[0] | ((unsigned)hi[1]<<16),
                                   (unsigned)hi[2] | ((unsigned)hi[3]<<16));
  *(uint2*)(wl + idx) = make_uint2((unsigned)lo[0] | ((unsigned)lo[1]<<16),
                                   (unsigned)lo[2] | ((unsigned)lo[3]<<16));
  #pragma unroll
  for (int off = 32; off >= 1; off >>= 1) bsum += __shfl_down(bsum, off);
  if (lane == 0) bias2[z*256 + co] = sc*(bias[co] - bsum);
}

// ---------------- K2: conv1x1 via MFMA (f16 hi/lo weights, raw f16 inputs) ------
__global__ __launch_bounds__(256, 3) void k_conv(
    const float* __restrict__ q, const float* __restrict__ kk,
    const u16* __restrict__ wh, const u16* __restrict__ wl,
    const float* __restrict__ bias2,
    u16* __restrict__ qe, u16* __restrict__ kt, u16* __restrict__ se)
{
  __shared__ u16 XT[64*256];   // 32KB
  const int tid = threadIdx.x;
  const int spt = blockIdx.x, bz = blockIdx.y;
  const int b = bz / 3, mode = bz - b*3;
  const int sp0 = spt*64;
  const float* X = (mode==0 ? q : kk) + (size_t)b*C_*N_;
  const int z = (mode==0) ? b : (mode==1 ? 4+b : 8);
  const u16* whp = wh + (size_t)z*8*256*32;
  const u16* wlp = wl + (size_t)z*8*256*32;
  const float* bp = bias2 + z*256;

  {
    int kc_l = tid & 15, spq = tid >> 4;
    #pragma unroll
    for (int i=0;i<16;i++){
      int kc = i*16 + kc_l;
      float4 v = *(const float4*)(X + (size_t)kc*N_ + sp0 + spq*4);
      float vv[4] = {v.x, v.y, v.z, v.w};
      #pragma unroll
      for (int e=0;e<4;e++){
        int sp = spq*4 + e;
        int byte = sp*512 + (((kc>>3) ^ (sp&7)) << 4) + (kc&7)*2;
        *(u16*)((char*)XT + byte) = f2h(vv[e]);
      }
    }
  }
  __syncthreads();

  const int wid = tid>>6, lane = tid&63, l15 = lane&15, lg = lane>>4;
  f32x4 acc[4][4];
  #pragma unroll
  for (int i=0;i<4;i++)
    #pragma unroll
    for (int j=0;j<4;j++) acc[i][j] = (f32x4)(0.f);

  #pragma unroll
  for (int ks=0; ks<8; ++ks){
    half8 xf[4];
    #pragma unroll
    for (int st=0; st<4; ++st)
      xf[st] = *(const half8*)((char*)XT + (st*16 + l15)*512 + (((ks*4+lg) ^ (l15&7)) << 4));
    #pragma unroll
    for (int ct=0; ct<4; ++ct){
      size_t woff = ((size_t)(ks*256 + wid*64 + ct*16 + l15))*32 + lg*8;
      half8 bh = *(const half8*)(whp + woff);
      half8 bl = *(const half8*)(wlp + woff);
      #pragma unroll
      for (int st=0; st<4; ++st){
        if (mode < 2){
          acc[st][ct] = __builtin_amdgcn_mfma_f32_16x16x32_f16(xf[st], bh, acc[st][ct], 0,0,0);
          acc[st][ct] = __builtin_amdgcn_mfma_f32_16x16x32_f16(xf[st], bl, acc[st][ct], 0,0,0);
        } else {
          acc[ct][st] = __builtin_amdgcn_mfma_f32_16x16x32_f16(bh, xf[st], acc[ct][st], 0,0,0);
          acc[ct][st] = __builtin_amdgcn_mfma_f32_16x16x32_f16(bl, xf[st], acc[ct][st], 0,0,0);
        }
      }
    }
  }

  if (mode < 2){
    u16* o = (mode==0 ? qe : kt);
    #pragma unroll
    for (int st=0; st<4; ++st){
      #pragma unroll
      for (int ct=0; ct<4; ++ct){
        int co = wid*64 + ct*16 + l15;
        float bb = bp[co];
        #pragma unroll
        for (int r=0;r<4;r++){
          int sp = sp0 + st*16 + lg*4 + r;
          o[(size_t)(b*N_ + sp)*C_ + co] = f2h(acc[st][ct][r] + bb);
        }
      }
    }
  } else {
    #pragma unroll
    for (int ct=0; ct<4; ++ct){
      #pragma unroll
      for (int st=0; st<4; ++st){
        #pragma unroll
        for (int r=0;r<4;r++){
          int co = wid*64 + ct*16 + lg*4 + r;
          float bb = bp[co];
          se[(size_t)(b*C_ + co)*M_ + sp0 + st*16 + l15] = f2h(acc[ct][st][r] + bb);
        }
      }
    }
  }
}

// ---------------- K3: swapped-QK flash attention + AdaAttN epilogue ----------------
// R13 verbatim (best passing: 232us k_attn / 242.6us total): 4 waves, quadrant QK
// (2 independent 4-deep chains), WT exchange, dbuf KT+SE, B1 full drain + Bmax/B2
// LDS-only, XCD swizzle, split E[s^2] accumulators, no setprio.
__global__ __launch_bounds__(256, 2) void k_attn(
    const float* __restrict__ q, const float* __restrict__ stq,
    const u16* __restrict__ qe_g, const u16* __restrict__ kt_g,
    const u16* __restrict__ se_g, float* __restrict__ out)
{
  __shared__ u16 KTs[2][KVB*256];     // 16KB x2, chunk16 ^ (row&7)
  __shared__ u16 SEs[2][C_*KVB];      // 16KB x2, chunk16 ^ ((c>>1)&3)
  __shared__ unsigned WTw[QB*16];     // P weights f16, 32 rows x 64B
  __shared__ float PMX[4][16];
  __shared__ float SRES[QB];
  __shared__ float LRUNS[2][QB];
  __shared__ int FLG[2];

  const int tid = threadIdx.x;
  const int wid = tid >> 6, lane = tid & 63;
  const int l15 = lane & 15, lg = lane >> 4;
  const int qg = wid & 1, mh = wid >> 1;
  // XCD-aware bijective swizzle (512 blocks, 8 XCDs): XCD pair <- one batch
  const int wg = blockIdx.x;
  const int sw = (wg & 7)*64 + (wg >> 3);
  const int b = sw >> 7;
  const int n0 = (sw & 127) * QB;

  half8 qf[8];
  {
    const u16* qb = qe_g + ((size_t)(b*N_ + n0 + qg*16 + l15))*C_;
    #pragma unroll
    for (int ks=0; ks<8; ++ks) qf[ks] = *(const half8*)(qb + ks*32 + lg*8);
  }

  int ktsrc[4], sesrc[4];
  #pragma unroll
  for (int i=0;i<4;i++){
    int g = (i*4 + wid)*64 + lane;
    int row = g >> 5, cin = g & 31;
    ktsrc[i] = row*512 + ((cin ^ (row & 7)) << 4);
    int c = g >> 2, mch = (g & 3) ^ ((c >> 1) & 3);
    sesrc[i] = c*8192 + mch*16;
  }
  const char* ktg = (const char*)kt_g + (size_t)b*M_*512;
  const char* seg = (const char*)se_g + (size_t)b*C_*M_*2;

  float m_run = -1e30f, lrun = 0.f;
  f32x4 accm[2][4], accs[2][4], accs2[2][4];
  #pragma unroll
  for (int i=0;i<2;i++)
    #pragma unroll
    for (int j=0;j<4;j++){
      accm[i][j] = (f32x4)(0.f); accs[i][j] = (f32x4)(0.f); accs2[i][j] = (f32x4)(0.f);
    }

  // prologue: stage tile 0 into buf 0
  #pragma unroll
  for (int i=0;i<4;i++){
    int o = (i*4 + wid)*1024;
    gll16(ktg + ktsrc[i], (char*)&KTs[0][0] + o);
    gll16(seg + sesrc[i], (char*)&SEs[0][0] + o);
  }

  for (int t=0; t<NT; ++t){
    const int buf = t & 1;
    __syncthreads();     // B1: full drain -> tile(t) staged; all waves past PV(t-1)

    // prefetch tile(t+1); stays in flight across the raw barriers below
    if (t+1 < NT){
      const int nb = buf ^ 1;
      int koff = (t+1)*(KVB*512);
      int soff = (t+1)*(KVB*2);
      #pragma unroll
      for (int i=0;i<4;i++){
        int o = (i*4 + wid)*1024;
        gll16(ktg + koff + ktsrc[i], (char*)&KTs[nb][0] + o);
        gll16(seg + soff + sesrc[i], (char*)&SEs[nb][0] + o);
      }
    }

    // ---- QK^T quadrant: D[m][q]; two independent 4-chains, summed ----
    f32x4 L0;
    {
      const char* ktb = (const char*)&KTs[buf][0];
      int krow = mh*16 + l15;
      f32x4 LA = (f32x4)(0.f), LB = (f32x4)(0.f);
      #pragma unroll
      for (int ks=0; ks<4; ++ks){
        half8 a0 = *(const half8*)(ktb + krow*512 + (((ks*4 + lg) ^ (l15 & 7)) << 4));
        half8 a1 = *(const half8*)(ktb + krow*512 + ((((ks+4)*4 + lg) ^ (l15 & 7)) << 4));
        LA = __builtin_amdgcn_mfma_f32_16x16x32_f16(a0, qf[ks],   LA, 0,0,0);
        LB = __builtin_amdgcn_mfma_f32_16x16x32_f16(a1, qf[ks+4], LB, 0,0,0);
      }
      #pragma unroll
      for (int r=0;r<4;r++) L0[r] = LA[r] + LB[r];
    }
    float pm = fmaxf(fmaxf(L0[0], L0[1]), fmaxf(L0[2], L0[3]));
    pm = fmaxf(pm, __shfl_xor(pm, 16));
    pm = fmaxf(pm, __shfl_xor(pm, 32));
    if (lg == 0) PMX[wid][l15] = pm;
    bar_lds();           // Bmax: exchange quadrant maxes (no vmcnt drain)

    float m_tile = fmaxf(pm, PMX[wid ^ 2][l15]);
    int flag = __any(m_tile > m_run + 8.0f);   // defer-max THR=8 (exp2 domain)
    float sv = 1.0f;
    if (flag){
      float mn = fmaxf(m_run, m_tile);
      sv = exp2f(m_run - mn);
      m_run = mn;
    }
    if (mh == 0 && lg == 0) SRES[qg*16 + l15] = sv;
    if (mh == 0 && lane == 0) FLG[qg] = flag;
    unsigned W0 = pkrtz(exp2f(L0[0]-m_run), exp2f(L0[1]-m_run));
    unsigned W1 = pkrtz(exp2f(L0[2]-m_run), exp2f(L0[3]-m_run));
    {
      int row = qg*16 + l15;
      int c16 = (mh*2 + (lg >> 1)) ^ ((l15 >> 1) & 3);
      *(uint2*)((char*)WTw + row*64 + (c16 << 4) + ((lg & 1) << 3)) = make_uint2(W0, W1);
    }
    float rs = sum2(W0) + sum2(W1);            // ROUNDED partial row-sum (own mh)
    rs += __shfl_xor(rs, 16);
    rs += __shfl_xor(rs, 32);
    lrun = lrun * sv + rs;
    bar_lds();           // B2: WT/SRES/FLG ready (no vmcnt drain; prefetch in flight)

    // conditional accumulator rescale (rare after warm-up)
    if (FLG[0] | FLG[1]){
      #pragma unroll
      for (int rt=0;rt<2;rt++){
        f32x4 s4 = *(const f32x4*)&SRES[rt*16 + lg*4];
        #pragma unroll
        for (int ct=0;ct<4;ct++){
          #pragma unroll
          for (int r=0;r<4;r++){
            accm[rt][ct][r] *= s4[r]; accs[rt][ct][r] *= s4[r]; accs2[rt][ct][r] *= s4[r];
          }
        }
      }
    }

    // ---- PV: all 6 MFMAs per ct independent (accm / accs / accs2 streams) ----
    {
      half8 a[2];
      #pragma unroll
      for (int rt=0;rt<2;rt++){
        int row = rt*16 + l15;
        a[rt] = *(const half8*)((char*)WTw + row*64 + ((lg ^ ((l15>>1)&3)) << 4));
      }
      const char* seb = (const char*)&SEs[buf][0];
      #pragma unroll
      for (int ct=0;ct<4;ct++){
        int c = wid*64 + ct*16 + l15;
        half8 v = *(const half8*)(seb + c*64 + ((lg ^ ((c>>1)&3)) << 4));
        half8 h2, l2;
        sq_hl(v, h2, l2);
        #pragma unroll
        for (int rt=0;rt<2;rt++){
          accm[rt][ct]  = __builtin_amdgcn_mfma_f32_16x16x32_f16(a[rt], v,  accm[rt][ct],  0,0,0);
          accs[rt][ct]  = __builtin_amdgcn_mfma_f32_16x16x32_f16(a[rt], h2, accs[rt][ct],  0,0,0);
          accs2[rt][ct] = __builtin_amdgcn_mfma_f32_16x16x32_f16(a[rt], l2, accs2[rt][ct], 0,0,0);
        }
      }
    }
  }

  if (lg == 0) LRUNS[mh][qg*16 + l15] = lrun;
  __syncthreads();

  // ---- epilogue: combine l, normalize, var=relu(E[s^2]-mean^2), cs = qn*std + mean ----
  #pragma unroll
  for (int rt=0;rt<2;rt++){
    f32x4 lv0 = *(const f32x4*)&LRUNS[0][rt*16 + lg*4];
    f32x4 lv1 = *(const f32x4*)&LRUNS[1][rt*16 + lg*4];
    f32x4 inv;
    #pragma unroll
    for (int r=0;r<4;r++) inv[r] = 1.f / (lv0[r] + lv1[r]);
    #pragma unroll
    for (int ct=0;ct<4;ct++){
      int c = wid*64 + ct*16 + l15;
      float2 st = *(const float2*)(stq + (size_t)(b*C_ + c)*2);
      size_t base = ((size_t)(b*C_ + c))*(size_t)N_ + (size_t)(n0 + rt*16 + lg*4);
      f32x4 qv = *(const f32x4*)(q + base);
      f32x4 res;
      #pragma unroll
      for (int r=0;r<4;r++){
        float mean = accm[rt][ct][r] * inv[r];
        float ms   = (accs[rt][ct][r] + accs2[rt][ct][r]) * inv[r];
        float sd   = sqrtf(fmaxf(ms - mean*mean, 0.f));
        float qn   = (qv[r] - st.x) * st.y;
        res[r] = qn * sd + mean;
      }
      *(f32x4*)(out + base) = res;
    }
  }
}

extern "C" void kernel_launch(void* const* d_in, const int* in_sizes, int n_in,
                              void* d_out, int out_size, void* d_ws, size_t ws_size,
                              hipStream_t stream){
  const float* q   = (const float*)d_in[0];
  const float* k   = (const float*)d_in[1];
  const float* wq  = (const float*)d_in[2];
  const float* bq  = (const float*)d_in[3];
  const float* wk  = (const float*)d_in[4];
  const float* bk  = (const float*)d_in[5];
  const float* wsw = (const float*)d_in[6];
  const float* bs  = (const float*)d_in[7];
  float* out = (float*)d_out;

  char* w = (char*)d_ws;
  float* stq = (float*)w;                          // 8KB
  float* stk = (float*)(w + 8192);                 // 8KB
  u16* wh    = (u16*)(w + 16384);                  // 1.125MB
  u16* wl    = (u16*)(w + 16384 + 1179648);        // 1.125MB
  float* bias2 = (float*)(w + 16384 + 2*1179648);  // 9KB -> pad 16KB
  char* big  = w + 16384 + 2*1179648 + 16384;
  u16* qe  = (u16*)big;                            // 8MB
  u16* kt  = qe + (size_t)B_*N_*C_;                // 8MB
  u16* se  = kt + (size_t)B_*M_*C_;                // 8MB

  k_stats<<<dim3(2048), dim3(256), 0, stream>>>(q, k, stq, stk);
  k_wprep<<<dim3(256, 9), dim3(64), 0, stream>>>(wq, bq, wk, bk, wsw, bs,
                                                 stq, stk, wh, wl, bias2);
  k_conv<<<dim3(64, 12), dim3(256), 0, stream>>>(q, k, wh, wl, bias2, qe, kt, se);
  k_attn<<<dim3(512), dim3(256), 0, stream>>>(q, stq, qe, kt, se, out);
}